// Round 1
// baseline (666.869 us; speedup 1.0000x reference)
//
#include <hip/hip_runtime.h>
#include <cstddef>

#define T_STEPS 205
#define BATCH   2048
#define NIN     33
#define NRNN    256
#define NKT     9           // K tiles of 32 covering k=0..287 (k=288 handled in epilogue)
#define BB      8           // batch rows per block
#define NTHREADS 512        // 8 waves
#define NTW     2           // n-tiles (16 cols) per wave

#define A_STRIDE  296       // fp16 elems per A row: >=289, mult of 8 (16B align), good bank pattern
#define WS_STRIDE 40        // fp16 elems per W-stage row: 32 + pad, mult of 8

typedef _Float16 half8 __attribute__((ext_vector_type(8)));
typedef float    f32x4 __attribute__((ext_vector_type(4)));

// A (LDS, fp16, rows 0..15, rows 8..15 stay zero):
//   k = 0..32   : x_t[b][0..32]
//   k = 33..287 : h[b][0..254]
//   slot 288    : h[b][255]   (rank-1 remainder, applied in epilogue via VALU)
// W fragments (fp16) are loaded ONCE into registers: 18 frags/wave = 72 VGPRs.

__global__ __launch_bounds__(NTHREADS, 2)
void leaky_rnn_kernel(const float* __restrict__ x,
                      const float* __restrict__ W,
                      const float* __restrict__ bias,
                      const float* __restrict__ h0,
                      float* __restrict__ out)
{
    __shared__ _Float16 A_lds[16 * A_STRIDE];
    __shared__ _Float16 Wst[NRNN * WS_STRIDE];

    const int tid  = threadIdx.x;
    const int lane = tid & 63;
    const int wave = tid >> 6;
    const int q    = lane >> 4;      // quad 0..3
    const int nlo  = lane & 15;
    const int b0   = blockIdx.x * BB;

    // zero all of A_lds (pad rows 8..15 must be 0 so padded MFMA rows are clean)
    for (int i = tid; i < 16 * A_STRIDE; i += NTHREADS) A_lds[i] = (_Float16)0.f;

    // ---- one-time: stage W rows 0..287 (fp32->fp16) and pull B-fragments into registers ----
    half8 wfrag[NTW][NKT];
    {
        const int c   = tid & 255;       // W column this thread packs
        const int oct = tid >> 8;        // 0..1
        #pragma unroll
        for (int kt = 0; kt < NKT; ++kt) {
            __syncthreads();             // prev frag reads done / A_lds zeroing ordered
            #pragma unroll
            for (int o2 = 0; o2 < 2; ++o2) {
                int o = oct + 2 * o2;    // 0..3 : k-octet within the 32-row chunk
                half8 pack;
                #pragma unroll
                for (int i = 0; i < 8; ++i) {
                    int r = o * 8 + i;   // row within chunk
                    pack[i] = (_Float16)W[(kt * 32 + r) * NRNN + c];  // coalesced over c
                }
                *(half8*)&Wst[c * WS_STRIDE + o * 8] = pack;         // [col][k] transposed
            }
            __syncthreads();
            #pragma unroll
            for (int nt = 0; nt < NTW; ++nt) {
                int n = (wave * NTW + nt) * 16 + nlo;
                // B-frag layout (16x16x32): n = lane&15, k = (lane>>4)*8 + i
                wfrag[nt][kt] = *(const half8*)&Wst[n * WS_STRIDE + q * 8];
            }
        }
    }

    // per-thread constants
    int   colg[NTW]; float bv[NTW]; float w288[NTW];
    #pragma unroll
    for (int nt = 0; nt < NTW; ++nt) {
        colg[nt] = (wave * NTW + nt) * 16 + nlo;
        bv[nt]   = bias[colg[nt]];
        w288[nt] = W[288 * NRNN + colg[nt]];     // last K row, applied via VALU
    }

    // x staging map (t-invariant): threads 0..263 each own one (b,i) element
    const int  xb   = tid / NIN;
    const int  xi   = tid - xb * NIN;
    const bool xact = (tid < BB * NIN);
    const int  xoff = (b0 + xb) * NIN + xi;

    // ---- initial state: x[0] + h0 into A_lds; h into registers ----
    float hreg[NTW][4];
    #pragma unroll
    for (int nt = 0; nt < NTW; ++nt)
        #pragma unroll
        for (int r = 0; r < 4; ++r) hreg[nt][r] = 0.f;

    if (xact) A_lds[xb * A_STRIDE + xi] = (_Float16)x[xoff];
    if (q < 2) {
        #pragma unroll
        for (int nt = 0; nt < NTW; ++nt) {
            int j    = colg[nt];
            int slot = (j == 255) ? 288 : (33 + j);
            #pragma unroll
            for (int r = 0; r < 4; ++r) {
                int b = q * 4 + r;
                float h = h0[(b0 + b) * NRNN + j];
                hreg[nt][r] = h;
                A_lds[b * A_STRIDE + slot] = (_Float16)h;
            }
        }
    }
    __syncthreads();

    const int am = nlo;   // A-frag row: m = lane&15
    for (int t = 0; t < T_STEPS; ++t) {
        // prefetch next x into registers (latency hidden under MFMA phase)
        float xv = 0.f;
        if (xact) xv = x[min(t + 1, T_STEPS - 1) * (BATCH * NIN) + xoff];

        f32x4 acc[NTW];
        #pragma unroll
        for (int nt = 0; nt < NTW; ++nt) acc[nt] = (f32x4){0.f, 0.f, 0.f, 0.f};

        #pragma unroll
        for (int kt = 0; kt < NKT; ++kt) {
            // A-frag: m = lane&15, k = kt*32 + (lane>>4)*8 + i  -> one ds_read_b128
            half8 af = *(const half8*)&A_lds[am * A_STRIDE + kt * 32 + q * 8];
            acc[0] = __builtin_amdgcn_mfma_f32_16x16x32_f16(af, wfrag[0][kt], acc[0], 0, 0, 0);
            acc[1] = __builtin_amdgcn_mfma_f32_16x16x32_f16(af, wfrag[1][kt], acc[1], 0, 0, 0);
        }

        // read old h[b][255] before the barrier (rows 8..15 read zeros, unused)
        float h255[4];
        #pragma unroll
        for (int r = 0; r < 4; ++r)
            h255[r] = (float)A_lds[(q * 4 + r) * A_STRIDE + 288];

        __syncthreads();   // all A_lds reads complete before rewrite

        // epilogue: C layout row=(lane>>4)*4+reg, col=lane&15 -> lanes q<2 own real rows 0..7
        if (q < 2) {
            #pragma unroll
            for (int nt = 0; nt < NTW; ++nt) {
                int j    = colg[nt];
                int slot = (j == 255) ? 288 : (33 + j);
                #pragma unroll
                for (int r = 0; r < 4; ++r) {
                    int b = q * 4 + r;
                    float pre = acc[nt][r] + bv[nt] + h255[r] * w288[nt];
                    float hn  = 0.8f * hreg[nt][r] + 0.2f * fmaxf(pre, 0.f);
                    hreg[nt][r] = hn;
                    out[(size_t)(t * BATCH + b0 + b) * NRNN + j] = hn;
                    A_lds[b * A_STRIDE + slot] = (_Float16)hn;
                }
            }
        }
        if (xact) A_lds[xb * A_STRIDE + xi] = (_Float16)xv;
        __syncthreads();
    }
}

extern "C" void kernel_launch(void* const* d_in, const int* in_sizes, int n_in,
                              void* d_out, int out_size, void* d_ws, size_t ws_size,
                              hipStream_t stream) {
    const float* x    = (const float*)d_in[0];
    const float* W    = (const float*)d_in[1];   // (289, 256) row-major
    const float* bias = (const float*)d_in[2];
    const float* h0   = (const float*)d_in[3];
    float* out = (float*)d_out;

    dim3 grid(BATCH / BB);      // 256 blocks -> 1 per CU
    dim3 block(NTHREADS);       // 8 waves
    leaky_rnn_kernel<<<grid, block, 0, stream>>>(x, W, bias, h0, out);
}

// Round 2
// 644.600 us; speedup vs baseline: 1.0345x; 1.0345x over previous
//
#include <hip/hip_runtime.h>
#include <cstddef>

#define T_STEPS 205
#define BATCH   2048
#define NIN     33
#define NRNN    256
#define NKT     9           // K tiles of 32 covering k=0..287 (k=288 handled in epilogue)
#define BB      8           // batch rows per block
#define NTHREADS 512        // 8 waves
#define NTW     2           // n-tiles (16 cols) per wave

#define A_STRIDE  296       // fp16 elems per A row: >=289, mult of 8 (16B align)
#define WS_STRIDE 40        // fp16 elems per W-stage row: 32 + pad, mult of 8

typedef _Float16 half8 __attribute__((ext_vector_type(8)));
typedef float    f32x4 __attribute__((ext_vector_type(4)));

// Barrier that waits ONLY on LDS ops (lgkmcnt), not global stores/loads.
// __syncthreads() would emit s_waitcnt vmcnt(0) and drain the out-stores and
// the x-prefetch every step -> that drain was the R1 bottleneck (3630 cyc/step
// with all pipes <18% busy). LDS visibility across the workgroup only needs
// lgkmcnt(0) + s_barrier.
__device__ __forceinline__ void lds_barrier() {
    asm volatile("s_waitcnt lgkmcnt(0)\n\ts_barrier" ::: "memory");
}

// A (LDS, fp16, double-buffered; rows 0..7 real, 8..15 stay zero):
//   k = 0..32   : x_t[b][0..32]
//   k = 33..287 : h[b][0..254]
//   slot 288    : h[b][255]   (rank-1 remainder, applied in epilogue via VALU)
// Step t reads buf p, writes h_{t+1}/x_{t+1} into buf 1-p; ONE barrier/step.
// W fragments (fp16) live in registers the whole kernel: 18 frags/wave.

__global__ __launch_bounds__(NTHREADS, 2)
void leaky_rnn_kernel(const float* __restrict__ x,
                      const float* __restrict__ W,
                      const float* __restrict__ bias,
                      const float* __restrict__ h0,
                      float* __restrict__ out)
{
    __shared__ _Float16 A_lds[2][16 * A_STRIDE];
    __shared__ _Float16 Wst[NRNN * WS_STRIDE];

    const int tid  = threadIdx.x;
    const int lane = tid & 63;
    const int wave = tid >> 6;
    const int q    = lane >> 4;      // quad 0..3
    const int nlo  = lane & 15;
    const int b0   = blockIdx.x * BB;

    // zero both A buffers (pad rows 8..15 must read as 0 forever)
    for (int i = tid; i < 2 * 16 * A_STRIDE; i += NTHREADS)
        A_lds[0][i] = (_Float16)0.f;   // flat over both buffers

    // ---- one-time: stage W rows 0..287 (fp32->fp16), pull B-frags to regs ----
    half8 wfrag[NTW][NKT];
    {
        const int c   = tid & 255;       // W column this thread packs
        const int oct = tid >> 8;        // 0..1
        #pragma unroll
        for (int kt = 0; kt < NKT; ++kt) {
            __syncthreads();             // init phase: full barrier is fine here
            #pragma unroll
            for (int o2 = 0; o2 < 2; ++o2) {
                int o = oct + 2 * o2;    // 0..3 : k-octet within the 32-row chunk
                half8 pack;
                #pragma unroll
                for (int i = 0; i < 8; ++i) {
                    int r = o * 8 + i;
                    pack[i] = (_Float16)W[(kt * 32 + r) * NRNN + c];  // coalesced over c
                }
                *(half8*)&Wst[c * WS_STRIDE + o * 8] = pack;          // [col][k] transposed
            }
            __syncthreads();
            #pragma unroll
            for (int nt = 0; nt < NTW; ++nt) {
                int n = (wave * NTW + nt) * 16 + nlo;
                // B-frag layout (16x16x32): n = lane&15, k = (lane>>4)*8 + i
                wfrag[nt][kt] = *(const half8*)&Wst[n * WS_STRIDE + q * 8];
            }
        }
    }

    // per-thread constants
    int   colg[NTW]; float bv[NTW]; float w288[NTW];
    #pragma unroll
    for (int nt = 0; nt < NTW; ++nt) {
        colg[nt] = (wave * NTW + nt) * 16 + nlo;
        bv[nt]   = bias[colg[nt]];
        w288[nt] = W[288 * NRNN + colg[nt]];     // last K row, applied via VALU
    }

    // x staging map (t-invariant): threads 0..263 each own one (b,i) element
    const int  xb   = tid / NIN;
    const int  xi   = tid - xb * NIN;
    const bool xact = (tid < BB * NIN);
    const int  xoff = (b0 + xb) * NIN + xi;

    // ---- initial state into buf 0: x[0] + h0; h also into registers ----
    float hreg[NTW][4];
    #pragma unroll
    for (int nt = 0; nt < NTW; ++nt)
        #pragma unroll
        for (int r = 0; r < 4; ++r) hreg[nt][r] = 0.f;

    if (xact) A_lds[0][xb * A_STRIDE + xi] = (_Float16)x[xoff];
    if (q < 2) {
        #pragma unroll
        for (int nt = 0; nt < NTW; ++nt) {
            int j    = colg[nt];
            int slot = (j == 255) ? 288 : (33 + j);
            #pragma unroll
            for (int r = 0; r < 4; ++r) {
                int b = q * 4 + r;
                float h = h0[(b0 + b) * NRNN + j];
                hreg[nt][r] = h;
                A_lds[0][b * A_STRIDE + slot] = (_Float16)h;
            }
        }
    }
    __syncthreads();   // end of init: full barrier once

    const int am = nlo;   // A-frag row: m = lane&15
    int p = 0;
    for (int t = 0; t < T_STEPS; ++t) {
        // prefetch next x into registers (vmcnt waited only at the consumer)
        float xv = 0.f;
        if (xact) xv = x[min(t + 1, T_STEPS - 1) * (BATCH * NIN) + xoff];

        f32x4 acc[NTW];
        #pragma unroll
        for (int nt = 0; nt < NTW; ++nt) acc[nt] = (f32x4){0.f, 0.f, 0.f, 0.f};

        const _Float16* __restrict__ Ar = A_lds[p];
        _Float16* __restrict__ Aw = A_lds[p ^ 1];

        #pragma unroll
        for (int kt = 0; kt < NKT; ++kt) {
            // A-frag: m = lane&15, k = kt*32 + (lane>>4)*8 + i  -> one ds_read_b128
            half8 af = *(const half8*)&Ar[am * A_STRIDE + kt * 32 + q * 8];
            acc[0] = __builtin_amdgcn_mfma_f32_16x16x32_f16(af, wfrag[0][kt], acc[0], 0, 0, 0);
            acc[1] = __builtin_amdgcn_mfma_f32_16x16x32_f16(af, wfrag[1][kt], acc[1], 0, 0, 0);
        }

        // old h[b][255] from the read buffer (safe: buf p is only rewritten in t+1)
        float h255[4];
        #pragma unroll
        for (int r = 0; r < 4; ++r)
            h255[r] = (float)Ar[(q * 4 + r) * A_STRIDE + 288];

        // epilogue writes go to the OTHER buffer -> no read/write hazard, no
        // barrier needed here. C layout row=(lane>>4)*4+reg, col=lane&15:
        // lanes q<2 own real rows 0..7.
        if (q < 2) {
            #pragma unroll
            for (int nt = 0; nt < NTW; ++nt) {
                int j    = colg[nt];
                int slot = (j == 255) ? 288 : (33 + j);
                #pragma unroll
                for (int r = 0; r < 4; ++r) {
                    int b = q * 4 + r;
                    float pre = acc[nt][r] + bv[nt] + h255[r] * w288[nt];
                    float hn  = 0.8f * hreg[nt][r] + 0.2f * fmaxf(pre, 0.f);
                    hreg[nt][r] = hn;
                    out[(size_t)(t * BATCH + b0 + b) * NRNN + j] = hn;
                    Aw[b * A_STRIDE + slot] = (_Float16)hn;
                }
            }
        }
        if (xact) Aw[xb * A_STRIDE + xi] = (_Float16)xv;

        lds_barrier();   // LDS-only wait: out-stores keep draining in background
        p ^= 1;
    }
}

extern "C" void kernel_launch(void* const* d_in, const int* in_sizes, int n_in,
                              void* d_out, int out_size, void* d_ws, size_t ws_size,
                              hipStream_t stream) {
    const float* x    = (const float*)d_in[0];
    const float* W    = (const float*)d_in[1];   // (289, 256) row-major
    const float* bias = (const float*)d_in[2];
    const float* h0   = (const float*)d_in[3];
    float* out = (float*)d_out;

    dim3 grid(BATCH / BB);      // 256 blocks -> 1 per CU
    dim3 block(NTHREADS);       // 8 waves
    leaky_rnn_kernel<<<grid, block, 0, stream>>>(x, W, bias, h0, out);
}